// Round 8
// baseline (290.354 us; speedup 1.0000x reference)
//
#include <hip/hip_runtime.h>

#define NTOK 16384
#define DIM 512
#define NTAU 4

typedef __attribute__((ext_vector_type(4))) float f32x4;
typedef __attribute__((ext_vector_type(8))) short bf16x8;   // 8 bf16 in 4 VGPRs
typedef __attribute__((ext_vector_type(4))) unsigned short u16x4;
typedef __attribute__((ext_vector_type(8))) unsigned short u16x8;
typedef unsigned int u32;

__device__ inline unsigned short f2bf(float f) {
    union { float f; unsigned int u; } v; v.f = f;
    unsigned int u = v.u + 0x7FFFu + ((v.u >> 16) & 1u);  // RNE
    return (unsigned short)(u >> 16);
}

__device__ inline void bf8_to_f32(u16x8 h, f32x4& a, f32x4& b) {
    union { unsigned int u; float f; } t;
#pragma unroll
    for (int e = 0; e < 4; e++) { t.u = ((unsigned int)h[e]) << 16; a[e] = t.f; }
#pragma unroll
    for (int e = 0; e < 4; e++) { t.u = ((unsigned int)h[4 + e]) << 16; b[e] = t.f; }
}

#define NTLOAD4(p) __builtin_nontemporal_load((const f32x4*)(p))

// async global -> LDS, 16 bytes per lane. LDS dest: wave-uniform base + lane*16.
__device__ __forceinline__ void gload16(const void* g, void* l) {
    __builtin_amdgcn_global_load_lds((const __attribute__((address_space(1))) u32*)g,
                                     (__attribute__((address_space(3))) u32*)l, 16, 0, 0);
}

// ---------------- K0: fp32 -> bf16 convert (all 4 weight mats, one launch) ----
__global__ void convert_all(const float* __restrict__ a, const float* __restrict__ b,
                            const float* __restrict__ c, const float* __restrict__ d,
                            unsigned short* __restrict__ oa, unsigned short* __restrict__ ob,
                            unsigned short* __restrict__ oc, unsigned short* __restrict__ od) {
    int i = blockIdx.x * 256 + threadIdx.x;   // 0..524287 (x4 units)
    const float* s; unsigned short* t; int off;
    if (i < 65536)       { s = a; t = oa; off = i; }
    else if (i < 131072) { s = b; t = ob; off = i - 65536; }
    else if (i < 327680) { s = c; t = oc; off = i - 131072; }
    else                 { s = d; t = od; off = i - 327680; }
    f32x4 v = ((const f32x4*)s)[off];
    u16x4 o;
    o[0] = f2bf(v[0]); o[1] = f2bf(v[1]); o[2] = f2bf(v[2]); o[3] = f2bf(v[3]);
    ((u16x4*)t)[off] = o;
}

// ---------------- K1: BOTH next-GEMMs in one launch (1024 blocks) ----------------
__global__ __launch_bounds__(256, 2) void gemm_next2(
    const float* __restrict__ T_t, const float* __restrict__ S_t,
    const unsigned short* __restrict__ Wtn, const unsigned short* __restrict__ Wsn,
    const float* __restrict__ btn, const float* __restrict__ bsn,
    unsigned short* __restrict__ t_next, unsigned short* __restrict__ s_next)
{
    __shared__ unsigned short lA[128][40];
    __shared__ unsigned short lB[128][40];
    const int tid = threadIdx.x;
    const int id = blockIdx.x;                    // 0..1023
    const int xcd = id & 7;
    const int rest = id >> 3;                     // 0..127
    const int mat = rest & 1;
    const int idx = rest >> 1;                    // 0..63
    const float* A = mat ? S_t : T_t;
    const unsigned short* W = mat ? Wsn : Wtn;
    const float* bias = mat ? bsn : btn;
    unsigned short* out = mat ? s_next : t_next;
    const int m0 = (xcd * 16 + (idx >> 2)) * 128;
    const int n0 = (idx & 3) * 128;
    const int lane = tid & 63;
    const int w = tid >> 6;
    const int wr = w >> 1, wc = w & 1;

    f32x4 acc[4][4];
#pragma unroll
    for (int i = 0; i < 4; i++)
#pragma unroll
        for (int j = 0; j < 4; j++) acc[i][j] = (f32x4){0.f, 0.f, 0.f, 0.f};

    const int arow = tid >> 3;
    const int acol = (tid & 7) * 4;
    const int brow = tid >> 2;
    const int bcol = (tid & 3) * 8;

    for (int k0 = 0; k0 < DIM; k0 += 32) {
#pragma unroll
        for (int i = 0; i < 4; i++) {
            int r = arow + 32 * i;
            f32x4 v = *(const f32x4*)(A + (size_t)(m0 + r) * DIM + k0 + acol);
            u16x4 o;
            o[0] = f2bf(v[0]); o[1] = f2bf(v[1]); o[2] = f2bf(v[2]); o[3] = f2bf(v[3]);
            *(u16x4*)&lA[r][acol] = o;
        }
#pragma unroll
        for (int i = 0; i < 2; i++) {
            int r = brow + 64 * i;
            u16x8 v = *(const u16x8*)(W + (size_t)(n0 + r) * DIM + k0 + bcol);
            *(u16x8*)&lB[r][bcol] = v;
        }
        __syncthreads();

        bf16x8 af[4], bfr[4];
#pragma unroll
        for (int i = 0; i < 4; i++)
            af[i] = *(const bf16x8*)&lA[wr * 64 + i * 16 + (lane & 15)][(lane >> 4) * 8];
#pragma unroll
        for (int j = 0; j < 4; j++)
            bfr[j] = *(const bf16x8*)&lB[wc * 64 + j * 16 + (lane & 15)][(lane >> 4) * 8];
#pragma unroll
        for (int i = 0; i < 4; i++)
#pragma unroll
            for (int j = 0; j < 4; j++)
                acc[i][j] = __builtin_amdgcn_mfma_f32_16x16x32_bf16(af[i], bfr[j], acc[i][j], 0, 0, 0);
        __syncthreads();
    }

#pragma unroll
    for (int j = 0; j < 4; j++) {
        int n = n0 + wc * 64 + j * 16 + (lane & 15);
        float bv = bias[n];
#pragma unroll
        for (int i = 0; i < 4; i++) {
            int mbase = m0 + wr * 64 + i * 16 + (lane >> 4) * 4;
#pragma unroll
            for (int r = 0; r < 4; r++)
                out[(size_t)(mbase + r) * DIM + n] = f2bf(acc[i][j][r] + bv);
        }
    }
}

// ---------------- K2a: dots + softmax -> w_all[n][8] ----------------
__global__ __launch_bounds__(256) void dots_kernel(
    const float* __restrict__ s_att, const float* __restrict__ t_spatial,
    const unsigned short* __restrict__ t_next, const unsigned short* __restrict__ s_next,
    float* __restrict__ w_all)
{
    const int lane = threadIdx.x & 63;
    const int id = blockIdx.x;
    const int n = (id & 7) * 2048 + (id >> 3) * 4 + (threadIdx.x >> 6);
    const int c = lane * 8;
    const size_t rb = (size_t)n * DIM + c;
    const float scale = 0.04419417382415922f;  // 1/sqrt(512)

    f32x4 tn_a, tn_b, sn_a, sn_b;
    bf8_to_f32(*(const u16x8*)(t_next + rb), tn_a, tn_b);
    bf8_to_f32(*(const u16x8*)(s_next + rb), sn_a, sn_b);

    float dws[NTAU], dwt[NTAU];
#pragma unroll
    for (int k = 0; k < NTAU; k++) {
        const size_t kb = ((size_t)k * NTOK + n) * DIM + c;
        f32x4 a0 = NTLOAD4(s_att + kb);
        f32x4 a1 = NTLOAD4(s_att + kb + 4);
        f32x4 b0 = NTLOAD4(t_spatial + kb);
        f32x4 b1 = NTLOAD4(t_spatial + kb + 4);
        dws[k] = a0[0]*sn_a[0]+a0[1]*sn_a[1]+a0[2]*sn_a[2]+a0[3]*sn_a[3]
               + a1[0]*sn_b[0]+a1[1]*sn_b[1]+a1[2]*sn_b[2]+a1[3]*sn_b[3];
        dwt[k] = b0[0]*tn_a[0]+b0[1]*tn_a[1]+b0[2]*tn_a[2]+b0[3]*tn_a[3]
               + b1[0]*tn_b[0]+b1[1]*tn_b[1]+b1[2]*tn_b[2]+b1[3]*tn_b[3];
    }
#pragma unroll
    for (int k = 0; k < NTAU; k++) {
        float v = dws[k];
#pragma unroll
        for (int off = 32; off; off >>= 1) v += __shfl_xor(v, off);
        dws[k] = v * scale;
        float u = dwt[k];
#pragma unroll
        for (int off = 32; off; off >>= 1) u += __shfl_xor(u, off);
        dwt[k] = u * scale;
    }

    float ms = fmaxf(fmaxf(dws[0], dws[1]), fmaxf(dws[2], dws[3]));
    float mt = fmaxf(fmaxf(dwt[0], dwt[1]), fmaxf(dwt[2], dwt[3]));
    f32x4 wsv, wtv;
    float ssum = 0.f, tsum = 0.f;
#pragma unroll
    for (int k = 0; k < NTAU; k++) {
        wsv[k] = __expf(dws[k] - ms); ssum += wsv[k];
        wtv[k] = __expf(dwt[k] - mt); tsum += wtv[k];
    }
    float rs = 1.f / ssum, rt = 1.f / tsum;
#pragma unroll
    for (int k = 0; k < NTAU; k++) { wsv[k] *= rs; wtv[k] *= rt; }

    if (lane == 0) {
        *(f32x4*)(w_all + (size_t)n * 8)     = wsv;
        *(f32x4*)(w_all + (size_t)n * 8 + 4) = wtv;
    }
}

// ---------------- K2b: weighted trend + gates -> Tf, Sf (bf16) ----------------
__global__ __launch_bounds__(256) void fusion_kernel(
    const float* __restrict__ T_t, const float* __restrict__ S_t,
    const float* __restrict__ t_att, const float* __restrict__ s_spatial,
    const unsigned short* __restrict__ t_next, const unsigned short* __restrict__ s_next,
    const float* __restrict__ w_all,
    unsigned short* __restrict__ Tf, unsigned short* __restrict__ Sf)
{
    const int lane = threadIdx.x & 63;
    const int id = blockIdx.x;
    const int n = (id & 7) * 2048 + (id >> 3) * 4 + (threadIdx.x >> 6);
    const int c = lane * 8;
    const size_t rb = (size_t)n * DIM + c;

    f32x4 wsv = *(const f32x4*)(w_all + (size_t)n * 8);       // uniform (broadcast)
    f32x4 wtv = *(const f32x4*)(w_all + (size_t)n * 8 + 4);

    f32x4 Tta = {0,0,0,0}, Ttb = {0,0,0,0}, Sta = {0,0,0,0}, Stb = {0,0,0,0};
#pragma unroll
    for (int k = 0; k < NTAU; k++) {
        const size_t kb = ((size_t)k * NTOK + n) * DIM + c;
        f32x4 ta = NTLOAD4(t_att + kb);
        f32x4 tb = NTLOAD4(t_att + kb + 4);
        f32x4 sa = NTLOAD4(s_spatial + kb);
        f32x4 sb = NTLOAD4(s_spatial + kb + 4);
        float wk = wsv[k], vk = wtv[k];
#pragma unroll
        for (int e = 0; e < 4; e++) {
            Tta[e] += wk * ta[e]; Ttb[e] += wk * tb[e];
            Sta[e] += vk * sa[e]; Stb[e] += vk * sb[e];
        }
    }

    f32x4 tn_a, tn_b, sn_a, sn_b;
    bf8_to_f32(*(const u16x8*)(t_next + rb), tn_a, tn_b);
    bf8_to_f32(*(const u16x8*)(s_next + rb), sn_a, sn_b);
    f32x4 Ta = NTLOAD4(T_t + rb);
    f32x4 Tb = NTLOAD4(T_t + rb + 4);
    f32x4 Sa = NTLOAD4(S_t + rb);
    f32x4 Sb = NTLOAD4(S_t + rb + 4);

    u16x8 oT, oS;
#pragma unroll
    for (int e = 0; e < 4; e++) {
        float gt_a = 1.f / (1.f + __expf(-tn_a[e]));
        float gt_b = 1.f / (1.f + __expf(-tn_b[e]));
        float gs_a = 1.f / (1.f + __expf(-sn_a[e]));
        float gs_b = 1.f / (1.f + __expf(-sn_b[e]));
        oT[e]     = f2bf(Ta[e] * gt_a + (1.f - gt_a) * Tta[e]);
        oT[4 + e] = f2bf(Tb[e] * gt_b + (1.f - gt_b) * Ttb[e]);
        oS[e]     = f2bf(Sa[e] * gs_a + (1.f - gs_a) * Sta[e]);
        oS[4 + e] = f2bf(Sb[e] * gs_b + (1.f - gs_b) * Stb[e]);
    }
    *(u16x8*)(Tf + rb) = oT;
    *(u16x8*)(Sf + rb) = oS;
}

// ---------------- K3: fused final GEMM, T/S wave-specialized ----------------
// BM=128 BN=32, 4 waves: w={0,1}=T-side (j half w), w={2,3}=S-side (j half w-2).
// Per wave: 8 m-frags x 1 j-frag x 3 groups; acc = 96 VGPR. launch_bounds(256,2)
// -> VGPR cap 256, NO spill; 56KB LDS dbuf -> 2 blocks/CU.
// Epilogue: exchange TS<->ST (bias pre-added) through reused LDS.
__global__ __launch_bounds__(256, 2) void gemm_final(
    const unsigned short* __restrict__ Tf, const unsigned short* __restrict__ Sf,
    const unsigned short* __restrict__ Wt, const unsigned short* __restrict__ Ws,
    const float* __restrict__ bt, const float* __restrict__ bs,
    float* __restrict__ out)
{
    __shared__ __align__(16) unsigned char smem[57344];
    auto lT = (unsigned short (*)[128][32])(smem);            // [2][128][32]
    auto lS = (unsigned short (*)[128][32])(smem + 16384);    // [2][128][32]
    auto lW = (unsigned short (*)[192][32])(smem + 32768);    // [2][192][32]
    auto ex = (float (*)[16][132])(smem);                     // [4][16][132] (aliased)

    const int tid = threadIdx.x;
    const int id = blockIdx.x;                    // 0..2047
    const int xcd = id & 7;
    const int idx = id >> 3;                      // 0..255
    const int m0 = (xcd * 16 + (idx >> 4)) * 128;
    const int j0 = (idx & 15) * 32;
    const int lane = tid & 63;
    const int w = tid >> 6;                       // 0..3
    const int side = w >> 1;                      // 0 = T, 1 = S
    const int jq = w & 1;                         // 16-col group within BN=32

    f32x4 acc[3][8];
#pragma unroll
    for (int g = 0; g < 3; g++)
#pragma unroll
        for (int i = 0; i < 8; i++) acc[g][i] = (f32x4){0.f, 0.f, 0.f, 0.f};

    const int srow = lane >> 2;   // 0..15
    const int sg   = lane & 3;    // physical granule

    // 28 chunk-loads (16 rows x 32 cols each) per K-step, 7 per wave.
    // chunks 0..7: lT; 8..15: lS; 16..27: lW (192 rows).
    auto stage = [&](int buf, int kt) {
        const int k0 = kt * 32;
#pragma unroll
        for (int i = 0; i < 7; i++) {
            const int ch = w * 7 + i;
            if (ch < 8) {
                const int row = ch * 16 + srow;
                const int lg = sg ^ ((row >> 1) & 3);
                gload16(Tf + (size_t)(m0 + row) * DIM + k0 + lg * 8, &lT[buf][ch * 16][0]);
            } else if (ch < 16) {
                const int row = (ch - 8) * 16 + srow;
                const int lg = sg ^ ((row >> 1) & 3);
                gload16(Sf + (size_t)(m0 + row) * DIM + k0 + lg * 8, &lS[buf][(ch - 8) * 16][0]);
            } else {
                const int rbse = (ch - 16) * 16;
                const int r = rbse + srow;               // 0..191
                const int lg = sg ^ ((r >> 1) & 3);
                const int g = r >> 5;                    // 0..5
                const unsigned short* src = (g < 3) ? Wt : Ws;
                const int wrow = (g < 3 ? g : g - 3) * DIM + j0 + (r & 31);
                gload16(src + (size_t)wrow * DIM + k0 + lg * 8, &lW[buf][rbse][0]);
            }
        }
    };

    stage(0, 0);
    __syncthreads();

    int cur = 0;
    for (int kt = 0; kt < 16; ++kt) {
        if (kt < 15) stage(cur ^ 1, kt + 1);

        unsigned short (*lA)[32] = side ? lS[cur] : lT[cur];
        bf16x8 ax[8], bw[3];
#pragma unroll
        for (int i = 0; i < 8; i++) {
            const int row = i * 16 + (lane & 15);
            const int pg = (lane >> 4) ^ ((row >> 1) & 3);
            ax[i] = *(const bf16x8*)&lA[row][pg * 8];
        }
#pragma unroll
        for (int g = 0; g < 3; g++) {
            const int r = (side * 3 + g) * 32 + jq * 16 + (lane & 15);
            const int pg = (lane >> 4) ^ ((r >> 1) & 3);
            bw[g] = *(const bf16x8*)&lW[cur][r][pg * 8];
        }
#pragma unroll
        for (int g = 0; g < 3; g++)
#pragma unroll
            for (int i = 0; i < 8; i++)
                acc[g][i] = __builtin_amdgcn_mfma_f32_16x16x32_bf16(ax[i], bw[g], acc[g][i], 0, 0, 0);

        __syncthreads();
        cur ^= 1;
    }

    // ---- epilogue: exchange the cross group (T-wave: TS out, needs ST) ----
    const int j = j0 + jq * 16 + (lane & 15);
    const float b0 = side ? bs[j]        : bt[j];         // gate bias
    const float b1 = side ? bs[512 + j]  : bt[512 + j];   // own-mix bias (TT / ST)
    const float b2 = side ? bs[1024 + j] : bt[1024 + j];  // cross/own (TS / SS)

    // T-wave exports TS = acc[2]+b2; S-wave exports ST = acc[1]+b1.
    const int col = lane & 15;
#pragma unroll
    for (int i = 0; i < 8; i++) {
        const int rowb = i * 16 + (lane >> 4) * 4;
        f32x4 v = side ? acc[1][i] : acc[2][i];
        const float bb = side ? b1 : b2;
        v[0] += bb; v[1] += bb; v[2] += bb; v[3] += bb;
        *(f32x4*)&ex[w][col][rowb] = v;
    }
    __syncthreads();

    float* obase = out + (side ? (size_t)NTOK * DIM : 0);
    const float bown = side ? b2 : b1;   // own mixed group: T: TT(+b1), S: SS(+b2)
    const int gown = side ? 2 : 1;
#pragma unroll
    for (int i = 0; i < 8; i++) {
        const int rowb = i * 16 + (lane >> 4) * 4;
        f32x4 oth = *(const f32x4*)&ex[w ^ 2][col][rowb];   // partner's export
#pragma unroll
        for (int r = 0; r < 4; r++) {
            const float gate = 1.f / (1.f + __expf(-(acc[0][i][r] + b0)));
            const float own = acc[gown][i][r] + bown;
            obase[(size_t)(m0 + rowb + r) * DIM + j] = gate * own + (1.f - gate) * oth[r];
        }
    }
}

extern "C" void kernel_launch(void* const* d_in, const int* in_sizes, int n_in,
                              void* d_out, int out_size, void* d_ws, size_t ws_size,
                              hipStream_t stream) {
    const float* T_t       = (const float*)d_in[0];
    const float* S_t       = (const float*)d_in[1];
    const float* t_att     = (const float*)d_in[2];
    const float* s_att     = (const float*)d_in[3];
    const float* t_spatial = (const float*)d_in[4];
    const float* s_spatial = (const float*)d_in[5];
    const float* W_t  = (const float*)d_in[6];
    const float* b_t  = (const float*)d_in[7];
    const float* W_tn = (const float*)d_in[8];
    const float* b_tn = (const float*)d_in[9];
    const float* W_s  = (const float*)d_in[10];
    const float* b_s  = (const float*)d_in[11];
    const float* W_sn = (const float*)d_in[12];
    const float* b_sn = (const float*)d_in[13];
    float* out = (float*)d_out;

    char* ws = (char*)d_ws;
    unsigned short* t_next = (unsigned short*)(ws + 0);          // 16.8 MB
    unsigned short* s_next = (unsigned short*)(ws + 16777216);
    unsigned short* Tf     = (unsigned short*)(ws + 33554432);
    unsigned short* Sf     = (unsigned short*)(ws + 50331648);
    unsigned short* Wtn_b  = (unsigned short*)(ws + 67108864);
    unsigned short* Wsn_b  = (unsigned short*)(ws + 67633152);
    unsigned short* Wt_b   = (unsigned short*)(ws + 68157440);
    unsigned short* Ws_b   = (unsigned short*)(ws + 69730304);
    float*          w_all  = (float*)(ws + 71303168);            // 512 KB

    convert_all<<<2048, 256, 0, stream>>>(W_tn, W_sn, W_t, W_s,
                                          Wtn_b, Wsn_b, Wt_b, Ws_b);

    gemm_next2<<<1024, 256, 0, stream>>>(T_t, S_t, Wtn_b, Wsn_b, b_tn, b_sn,
                                         t_next, s_next);

    dots_kernel<<<4096, 256, 0, stream>>>(s_att, t_spatial, t_next, s_next, w_all);

    fusion_kernel<<<4096, 256, 0, stream>>>(T_t, S_t, t_att, s_spatial,
                                            t_next, s_next, w_all, Tf, Sf);

    gemm_final<<<2048, 256, 0, stream>>>(Tf, Sf, Wt_b, Ws_b, b_t, b_s, out);
}

// Round 9
// 280.048 us; speedup vs baseline: 1.0368x; 1.0368x over previous
//
#include <hip/hip_runtime.h>

#define NTOK 16384
#define DIM 512
#define NTAU 4

typedef __attribute__((ext_vector_type(4))) float f32x4;
typedef __attribute__((ext_vector_type(8))) short bf16x8;   // 8 bf16 in 4 VGPRs
typedef __attribute__((ext_vector_type(4))) unsigned short u16x4;
typedef __attribute__((ext_vector_type(8))) unsigned short u16x8;
typedef unsigned int u32;

__device__ inline unsigned short f2bf(float f) {
    union { float f; unsigned int u; } v; v.f = f;
    unsigned int u = v.u + 0x7FFFu + ((v.u >> 16) & 1u);  // RNE
    return (unsigned short)(u >> 16);
}

__device__ inline void bf8_to_f32(u16x8 h, f32x4& a, f32x4& b) {
    union { unsigned int u; float f; } t;
#pragma unroll
    for (int e = 0; e < 4; e++) { t.u = ((unsigned int)h[e]) << 16; a[e] = t.f; }
#pragma unroll
    for (int e = 0; e < 4; e++) { t.u = ((unsigned int)h[4 + e]) << 16; b[e] = t.f; }
}

#define NTLOAD4(p) __builtin_nontemporal_load((const f32x4*)(p))

// async global -> LDS, 16 bytes per lane. LDS dest: wave-uniform base + lane*16.
__device__ __forceinline__ void gload16(const void* g, void* l) {
    __builtin_amdgcn_global_load_lds((const __attribute__((address_space(1))) u32*)g,
                                     (__attribute__((address_space(3))) u32*)l, 16, 0, 0);
}

// ---------------- K0: fp32 -> bf16 convert (all 4 weight mats, one launch) ----
__global__ void convert_all(const float* __restrict__ a, const float* __restrict__ b,
                            const float* __restrict__ c, const float* __restrict__ d,
                            unsigned short* __restrict__ oa, unsigned short* __restrict__ ob,
                            unsigned short* __restrict__ oc, unsigned short* __restrict__ od) {
    int i = blockIdx.x * 256 + threadIdx.x;   // 0..524287 (x4 units)
    const float* s; unsigned short* t; int off;
    if (i < 65536)       { s = a; t = oa; off = i; }
    else if (i < 131072) { s = b; t = ob; off = i - 65536; }
    else if (i < 327680) { s = c; t = oc; off = i - 131072; }
    else                 { s = d; t = od; off = i - 327680; }
    f32x4 v = ((const f32x4*)s)[off];
    u16x4 o;
    o[0] = f2bf(v[0]); o[1] = f2bf(v[1]); o[2] = f2bf(v[2]); o[3] = f2bf(v[3]);
    ((u16x4*)t)[off] = o;
}

// ---------------- K1: BOTH next-GEMMs in one launch (1024 blocks) ----------------
__global__ __launch_bounds__(256, 2) void gemm_next2(
    const float* __restrict__ T_t, const float* __restrict__ S_t,
    const unsigned short* __restrict__ Wtn, const unsigned short* __restrict__ Wsn,
    const float* __restrict__ btn, const float* __restrict__ bsn,
    unsigned short* __restrict__ t_next, unsigned short* __restrict__ s_next)
{
    __shared__ unsigned short lA[128][40];
    __shared__ unsigned short lB[128][40];
    const int tid = threadIdx.x;
    const int id = blockIdx.x;                    // 0..1023
    const int xcd = id & 7;
    const int rest = id >> 3;                     // 0..127
    const int mat = rest & 1;
    const int idx = rest >> 1;                    // 0..63
    const float* A = mat ? S_t : T_t;
    const unsigned short* W = mat ? Wsn : Wtn;
    const float* bias = mat ? bsn : btn;
    unsigned short* out = mat ? s_next : t_next;
    const int m0 = (xcd * 16 + (idx >> 2)) * 128;
    const int n0 = (idx & 3) * 128;
    const int lane = tid & 63;
    const int w = tid >> 6;
    const int wr = w >> 1, wc = w & 1;

    f32x4 acc[4][4];
#pragma unroll
    for (int i = 0; i < 4; i++)
#pragma unroll
        for (int j = 0; j < 4; j++) acc[i][j] = (f32x4){0.f, 0.f, 0.f, 0.f};

    const int arow = tid >> 3;
    const int acol = (tid & 7) * 4;
    const int brow = tid >> 2;
    const int bcol = (tid & 3) * 8;

    for (int k0 = 0; k0 < DIM; k0 += 32) {
#pragma unroll
        for (int i = 0; i < 4; i++) {
            int r = arow + 32 * i;
            f32x4 v = *(const f32x4*)(A + (size_t)(m0 + r) * DIM + k0 + acol);
            u16x4 o;
            o[0] = f2bf(v[0]); o[1] = f2bf(v[1]); o[2] = f2bf(v[2]); o[3] = f2bf(v[3]);
            *(u16x4*)&lA[r][acol] = o;
        }
#pragma unroll
        for (int i = 0; i < 2; i++) {
            int r = brow + 64 * i;
            u16x8 v = *(const u16x8*)(W + (size_t)(n0 + r) * DIM + k0 + bcol);
            *(u16x8*)&lB[r][bcol] = v;
        }
        __syncthreads();

        bf16x8 af[4], bfr[4];
#pragma unroll
        for (int i = 0; i < 4; i++)
            af[i] = *(const bf16x8*)&lA[wr * 64 + i * 16 + (lane & 15)][(lane >> 4) * 8];
#pragma unroll
        for (int j = 0; j < 4; j++)
            bfr[j] = *(const bf16x8*)&lB[wc * 64 + j * 16 + (lane & 15)][(lane >> 4) * 8];
#pragma unroll
        for (int i = 0; i < 4; i++)
#pragma unroll
            for (int j = 0; j < 4; j++)
                acc[i][j] = __builtin_amdgcn_mfma_f32_16x16x32_bf16(af[i], bfr[j], acc[i][j], 0, 0, 0);
        __syncthreads();
    }

#pragma unroll
    for (int j = 0; j < 4; j++) {
        int n = n0 + wc * 64 + j * 16 + (lane & 15);
        float bv = bias[n];
#pragma unroll
        for (int i = 0; i < 4; i++) {
            int mbase = m0 + wr * 64 + i * 16 + (lane >> 4) * 4;
#pragma unroll
            for (int r = 0; r < 4; r++)
                out[(size_t)(mbase + r) * DIM + n] = f2bf(acc[i][j][r] + bv);
        }
    }
}

// ---------------- K2a: dots + softmax -> w_all[n][8] ----------------
__global__ __launch_bounds__(256) void dots_kernel(
    const float* __restrict__ s_att, const float* __restrict__ t_spatial,
    const unsigned short* __restrict__ t_next, const unsigned short* __restrict__ s_next,
    float* __restrict__ w_all)
{
    const int lane = threadIdx.x & 63;
    const int id = blockIdx.x;
    const int n = (id & 7) * 2048 + (id >> 3) * 4 + (threadIdx.x >> 6);
    const int c = lane * 8;
    const size_t rb = (size_t)n * DIM + c;
    const float scale = 0.04419417382415922f;  // 1/sqrt(512)

    f32x4 tn_a, tn_b, sn_a, sn_b;
    bf8_to_f32(*(const u16x8*)(t_next + rb), tn_a, tn_b);
    bf8_to_f32(*(const u16x8*)(s_next + rb), sn_a, sn_b);

    float dws[NTAU], dwt[NTAU];
#pragma unroll
    for (int k = 0; k < NTAU; k++) {
        const size_t kb = ((size_t)k * NTOK + n) * DIM + c;
        f32x4 a0 = NTLOAD4(s_att + kb);
        f32x4 a1 = NTLOAD4(s_att + kb + 4);
        f32x4 b0 = NTLOAD4(t_spatial + kb);
        f32x4 b1 = NTLOAD4(t_spatial + kb + 4);
        dws[k] = a0[0]*sn_a[0]+a0[1]*sn_a[1]+a0[2]*sn_a[2]+a0[3]*sn_a[3]
               + a1[0]*sn_b[0]+a1[1]*sn_b[1]+a1[2]*sn_b[2]+a1[3]*sn_b[3];
        dwt[k] = b0[0]*tn_a[0]+b0[1]*tn_a[1]+b0[2]*tn_a[2]+b0[3]*tn_a[3]
               + b1[0]*tn_b[0]+b1[1]*tn_b[1]+b1[2]*tn_b[2]+b1[3]*tn_b[3];
    }
#pragma unroll
    for (int k = 0; k < NTAU; k++) {
        float v = dws[k];
#pragma unroll
        for (int off = 32; off; off >>= 1) v += __shfl_xor(v, off);
        dws[k] = v * scale;
        float u = dwt[k];
#pragma unroll
        for (int off = 32; off; off >>= 1) u += __shfl_xor(u, off);
        dwt[k] = u * scale;
    }

    float ms = fmaxf(fmaxf(dws[0], dws[1]), fmaxf(dws[2], dws[3]));
    float mt = fmaxf(fmaxf(dwt[0], dwt[1]), fmaxf(dwt[2], dwt[3]));
    f32x4 wsv, wtv;
    float ssum = 0.f, tsum = 0.f;
#pragma unroll
    for (int k = 0; k < NTAU; k++) {
        wsv[k] = __expf(dws[k] - ms); ssum += wsv[k];
        wtv[k] = __expf(dwt[k] - mt); tsum += wtv[k];
    }
    float rs = 1.f / ssum, rt = 1.f / tsum;
#pragma unroll
    for (int k = 0; k < NTAU; k++) { wsv[k] *= rs; wtv[k] *= rt; }

    if (lane == 0) {
        *(f32x4*)(w_all + (size_t)n * 8)     = wsv;
        *(f32x4*)(w_all + (size_t)n * 8 + 4) = wtv;
    }
}

// ---------------- K2b: weighted trend + gates -> Tf, Sf (bf16) ----------------
__global__ __launch_bounds__(256) void fusion_kernel(
    const float* __restrict__ T_t, const float* __restrict__ S_t,
    const float* __restrict__ t_att, const float* __restrict__ s_spatial,
    const unsigned short* __restrict__ t_next, const unsigned short* __restrict__ s_next,
    const float* __restrict__ w_all,
    unsigned short* __restrict__ Tf, unsigned short* __restrict__ Sf)
{
    const int lane = threadIdx.x & 63;
    const int id = blockIdx.x;
    const int n = (id & 7) * 2048 + (id >> 3) * 4 + (threadIdx.x >> 6);
    const int c = lane * 8;
    const size_t rb = (size_t)n * DIM + c;

    f32x4 wsv = *(const f32x4*)(w_all + (size_t)n * 8);       // uniform (broadcast)
    f32x4 wtv = *(const f32x4*)(w_all + (size_t)n * 8 + 4);

    f32x4 Tta = {0,0,0,0}, Ttb = {0,0,0,0}, Sta = {0,0,0,0}, Stb = {0,0,0,0};
#pragma unroll
    for (int k = 0; k < NTAU; k++) {
        const size_t kb = ((size_t)k * NTOK + n) * DIM + c;
        f32x4 ta = NTLOAD4(t_att + kb);
        f32x4 tb = NTLOAD4(t_att + kb + 4);
        f32x4 sa = NTLOAD4(s_spatial + kb);
        f32x4 sb = NTLOAD4(s_spatial + kb + 4);
        float wk = wsv[k], vk = wtv[k];
#pragma unroll
        for (int e = 0; e < 4; e++) {
            Tta[e] += wk * ta[e]; Ttb[e] += wk * tb[e];
            Sta[e] += vk * sa[e]; Stb[e] += vk * sb[e];
        }
    }

    f32x4 tn_a, tn_b, sn_a, sn_b;
    bf8_to_f32(*(const u16x8*)(t_next + rb), tn_a, tn_b);
    bf8_to_f32(*(const u16x8*)(s_next + rb), sn_a, sn_b);
    f32x4 Ta = NTLOAD4(T_t + rb);
    f32x4 Tb = NTLOAD4(T_t + rb + 4);
    f32x4 Sa = NTLOAD4(S_t + rb);
    f32x4 Sb = NTLOAD4(S_t + rb + 4);

    u16x8 oT, oS;
#pragma unroll
    for (int e = 0; e < 4; e++) {
        float gt_a = 1.f / (1.f + __expf(-tn_a[e]));
        float gt_b = 1.f / (1.f + __expf(-tn_b[e]));
        float gs_a = 1.f / (1.f + __expf(-sn_a[e]));
        float gs_b = 1.f / (1.f + __expf(-sn_b[e]));
        oT[e]     = f2bf(Ta[e] * gt_a + (1.f - gt_a) * Tta[e]);
        oT[4 + e] = f2bf(Tb[e] * gt_b + (1.f - gt_b) * Ttb[e]);
        oS[e]     = f2bf(Sa[e] * gs_a + (1.f - gs_a) * Sta[e]);
        oS[4 + e] = f2bf(Sb[e] * gs_b + (1.f - gs_b) * Stb[e]);
    }
    *(u16x8*)(Tf + rb) = oT;
    *(u16x8*)(Sf + rb) = oS;
}

// ---------------- K3: fused final GEMM, T/S-specialized, 8 waves ----------------
// BM=128 BN=32; 512 thr = 8 waves: side(2) x m-half(2) x j-quarter(2).
// Per wave: 4 m-frags x 1 j-frag x 3 groups -> acc = 48 VGPR; lb(512,2) cap 128.
// LDS arena [2][448][32] bf16 (57KB): rows 0-127 Tf, 128-255 Sf, 256-447 W.
// Addresses hoisted out of K-loop (gp[] advanced +=32/kt; LDS offsets const).
__global__ __launch_bounds__(512, 2) void gemm_final(
    const unsigned short* __restrict__ Tf, const unsigned short* __restrict__ Sf,
    const unsigned short* __restrict__ Wt, const unsigned short* __restrict__ Ws,
    const float* __restrict__ bt, const float* __restrict__ bs,
    float* __restrict__ out)
{
    __shared__ __align__(16) unsigned char smem[57344];   // 2 x 28672 B buffers
    const int tid = threadIdx.x;
    const int id = blockIdx.x;                    // 0..2047
    const int xcd = id & 7;
    const int idx = id >> 3;                      // 0..255
    const int m0 = (xcd * 16 + (idx >> 4)) * 128;
    const int j0 = (idx & 15) * 32;
    const int lane = tid & 63;
    const int w = tid >> 6;                       // 0..7
    const int side = w >> 2;                      // 0 = T, 1 = S
    const int mh = (w >> 1) & 1;                  // m half
    const int jq = w & 1;                         // 16-col group within BN=32

    f32x4 acc[3][4];
#pragma unroll
    for (int g = 0; g < 3; g++)
#pragma unroll
        for (int i = 0; i < 4; i++) acc[g][i] = (f32x4){0.f, 0.f, 0.f, 0.f};

    const int srow = lane >> 2;   // 0..15
    const int sg   = lane & 3;    // physical granule

    // ---- precompute this wave's staging chunks (28 chunks of 16 rows x 32 cols) --
    // chunk ch: dest bytes [ch*1024, +1024) in buffer; wave w owns ch = i*8+w, i<4.
    const unsigned short* gp[4];
    int nvalid[4];
#pragma unroll
    for (int i = 0; i < 4; i++) {
        const int ch = i * 8 + w;
        nvalid[i] = (ch < 28);
        const unsigned short* p = Tf;
        if (ch < 8) {
            const int trow = ch * 16 + srow;
            const int lg = sg ^ ((trow >> 1) & 3);
            p = Tf + (size_t)(m0 + trow) * DIM + lg * 8;
        } else if (ch < 16) {
            const int trow = (ch - 8) * 16 + srow;
            const int lg = sg ^ ((trow >> 1) & 3);
            p = Sf + (size_t)(m0 + trow) * DIM + lg * 8;
        } else if (ch < 28) {
            const int r = (ch - 16) * 16 + srow;            // 0..191
            const int lg = sg ^ ((r >> 1) & 3);
            const int g = r >> 5;                           // 0..5
            const unsigned short* src = (g < 3) ? Wt : Ws;
            const int wrow = (g < 3 ? g : g - 3) * DIM + j0 + (r & 31);
            p = src + (size_t)wrow * DIM + lg * 8;
        }
        gp[i] = p;
    }

    // ---- precompute LDS read byte-offsets (K-invariant) ----
    int axo[4], bwo[3];
#pragma unroll
    for (int i = 0; i < 4; i++) {
        const int row = mh * 64 + i * 16 + (lane & 15);
        const int pg = (lane >> 4) ^ ((row >> 1) & 3);
        axo[i] = ((side * 128 + row) * 32 + pg * 8) * 2;
    }
#pragma unroll
    for (int g = 0; g < 3; g++) {
        const int r = (side * 3 + g) * 32 + jq * 16 + (lane & 15);
        const int pg = (lane >> 4) ^ ((r >> 1) & 3);
        bwo[g] = ((256 + r) * 32 + pg * 8) * 2;
    }

    auto stage = [&](int buf) {
#pragma unroll
        for (int i = 0; i < 4; i++) {
            if (nvalid[i])
                gload16(gp[i], smem + buf * 28672 + (i * 8 + w) * 1024);
        }
    };

    stage(0);
    __syncthreads();

    int cur = 0;
    for (int kt = 0; kt < 16; ++kt) {
        if (kt < 15) {
#pragma unroll
            for (int i = 0; i < 4; i++) gp[i] += 32;
            stage(cur ^ 1);
        }

        const unsigned char* base = smem + cur * 28672;
        bf16x8 ax[4], bw[3];
#pragma unroll
        for (int i = 0; i < 4; i++) ax[i] = *(const bf16x8*)(base + axo[i]);
#pragma unroll
        for (int g = 0; g < 3; g++) bw[g] = *(const bf16x8*)(base + bwo[g]);
#pragma unroll
        for (int g = 0; g < 3; g++)
#pragma unroll
            for (int i = 0; i < 4; i++)
                acc[g][i] = __builtin_amdgcn_mfma_f32_16x16x32_bf16(ax[i], bw[g], acc[g][i], 0, 0, 0);

        __syncthreads();
        cur ^= 1;
    }

    // ---- epilogue: cross-group exchange via LDS (partner wave = w ^ 4) ----
    const int j = j0 + jq * 16 + (lane & 15);
    const float b0 = side ? bs[j]        : bt[j];         // gate bias
    const float b1 = side ? bs[512 + j]  : bt[512 + j];   // TT / ST bias
    const float b2 = side ? bs[1024 + j] : bt[1024 + j];  // TS / SS bias

    float* exbase = (float*)smem;                         // ex[8][16][68]
    const int col = lane & 15;
#pragma unroll
    for (int i = 0; i < 4; i++) {
        const int rowb = i * 16 + (lane >> 4) * 4;        // 0..63 within half
        f32x4 v = side ? acc[1][i] : acc[2][i];           // S exports ST, T exports TS
        const float bb = side ? b1 : b2;
        v[0] += bb; v[1] += bb; v[2] += bb; v[3] += bb;
        *(f32x4*)(exbase + ((w * 16 + col) * 68) + rowb) = v;
    }
    __syncthreads();

    float* obase = out + (side ? (size_t)NTOK * DIM : 0);
    const float bown = side ? b2 : b1;                    // own mixed: T->TT, S->SS
    const int pw = w ^ 4;
#pragma unroll
    for (int i = 0; i < 4; i++) {
        const int rowb = i * 16 + (lane >> 4) * 4;
        f32x4 oth = *(const f32x4*)(exbase + ((pw * 16 + col) * 68) + rowb);
        f32x4 own = side ? acc[2][i] : acc[1][i];
#pragma unroll
        for (int r = 0; r < 4; r++) {
            const float gate = 1.f / (1.f + __expf(-(acc[0][i][r] + b0)));
            const float ov = own[r] + bown;
            obase[(size_t)(m0 + mh * 64 + rowb + r) * DIM + j] = gate * ov + (1.f - gate) * oth[r];
        }
    }
}

extern "C" void kernel_launch(void* const* d_in, const int* in_sizes, int n_in,
                              void* d_out, int out_size, void* d_ws, size_t ws_size,
                              hipStream_t stream) {
    const float* T_t       = (const float*)d_in[0];
    const float* S_t       = (const float*)d_in[1];
    const float* t_att     = (const float*)d_in[2];
    const float* s_att     = (const float*)d_in[3];
    const float* t_spatial = (const float*)d_in[4];
    const float* s_spatial = (const float*)d_in[5];
    const float* W_t  = (const float*)d_in[6];
    const float* b_t  = (const float*)d_in[7];
    const float* W_tn = (const float*)d_in[8];
    const float* b_tn = (const float*)d_in[9];
    const float* W_s  = (const float*)d_in[10];
    const float* b_s  = (const float*)d_in[11];
    const float* W_sn = (const float*)d_in[12];
    const float* b_sn = (const float*)d_in[13];
    float* out = (float*)d_out;

    char* ws = (char*)d_ws;
    unsigned short* t_next = (unsigned short*)(ws + 0);          // 16.8 MB
    unsigned short* s_next = (unsigned short*)(ws + 16777216);
    unsigned short* Tf     = (unsigned short*)(ws + 33554432);
    unsigned short* Sf     = (unsigned short*)(ws + 50331648);
    unsigned short* Wtn_b  = (unsigned short*)(ws + 67108864);
    unsigned short* Wsn_b  = (unsigned short*)(ws + 67633152);
    unsigned short* Wt_b   = (unsigned short*)(ws + 68157440);
    unsigned short* Ws_b   = (unsigned short*)(ws + 69730304);
    float*          w_all  = (float*)(ws + 71303168);            // 512 KB

    convert_all<<<2048, 256, 0, stream>>>(W_tn, W_sn, W_t, W_s,
                                          Wtn_b, Wsn_b, Wt_b, Ws_b);

    gemm_next2<<<1024, 256, 0, stream>>>(T_t, S_t, Wtn_b, Wsn_b, b_tn, b_sn,
                                         t_next, s_next);

    dots_kernel<<<4096, 256, 0, stream>>>(s_att, t_spatial, t_next, s_next, w_all);

    fusion_kernel<<<4096, 256, 0, stream>>>(T_t, S_t, t_att, s_spatial,
                                            t_next, s_next, w_all, Tf, Sf);

    gemm_final<<<2048, 512, 0, stream>>>(Tf, Sf, Wt_b, Ws_b, b_t, b_s, out);
}